// Round 3
// baseline (469.154 us; speedup 1.0000x reference)
//
#include <hip/hip_runtime.h>
#include <hip/hip_bf16.h>

typedef float f32x4 __attribute__((ext_vector_type(4)));
typedef short s16x8 __attribute__((ext_vector_type(8)));

#define DEVI __device__ __forceinline__

DEVI unsigned short f2bf(float f) {
    return __builtin_bit_cast(unsigned short, __float2bfloat16(f));
}

// Geometry: B=4, C=128, H=W=360, r=9, h=w=40, T=1600 tokens, R2=81 features.
// token t = hh*40+ww, feature k = ch*9+cw, pixel (ch*40+hh, cw*40+ww).

// ---------------------------------------------------------------------------
// Kernel 0: convert Wconv f32[128][128] -> bf16 (L2-resident A operand).
__global__ __launch_bounds__(256) void k_wprep(
    const float* __restrict__ W, unsigned short* __restrict__ Wbf)
{
    const int i = blockIdx.x * 256 + threadIdx.x; // grid 64*256 = 16384
    Wbf[i] = f2bf(W[i]);
}

// ---------------------------------------------------------------------------
// Kernel 1: 1x1 conv GEMM, NO LDS: B-frags gathered straight from global x
// (8 coalesced dword loads per frag), A-frags = bf16 W rows (L1-resident).
// No barriers -> pure streaming; memory-bound.
// XR: bf16 [bo=512][81][1600]
__global__ __launch_bounds__(256, 3) void k_conv(
    const float* __restrict__ x, const unsigned short* __restrict__ Wbf,
    const float* __restrict__ bcv, unsigned short* __restrict__ XR)
{
    const int tid = threadIdx.x;
    int bid = blockIdx.x;
    const int rb = bid % 10; bid /= 10;
    const int cw = bid % 9;  bid /= 9;
    const int ch = bid % 9;  const int b = bid / 9;
    const int H0 = ch * 40 + rb * 4, w0 = cw * 40;
    const int kfeat = ch * 9 + cw;
    const int t0 = rb * 160;

    const int lane = tid & 63, wid = tid >> 6;
    const int wm = wid >> 1, wn = wid & 1;
    const int lr = lane & 15, lg = lane >> 4;

    // per-nt pixel base pointers (lane-dependent)
    const float* xb = x + (size_t)b * 128 * 129600;
    const float* pb[5];
#pragma unroll
    for (int nt = 0; nt < 5; ++nt) {
        const int tl = wn * 80 + nt * 16 + lr;
        pb[nt] = xb + (size_t)(H0 + tl / 40) * 360 + (w0 + tl % 40);
    }

    f32x4 acc[4][5] = {};
#pragma unroll
    for (int kk = 0; kk < 4; ++kk) {
        const int c0 = kk * 32 + lg * 8;
        s16x8 af[4];
#pragma unroll
        for (int mt = 0; mt < 4; ++mt)
            af[mt] = *reinterpret_cast<const s16x8*>(
                Wbf + (wm * 64 + mt * 16 + lr) * 128 + c0);
        s16x8 bfr[5];
#pragma unroll
        for (int nt = 0; nt < 5; ++nt) {
            const float* p = pb[nt] + (size_t)c0 * 129600;
            float f[8];
#pragma unroll
            for (int e = 0; e < 8; ++e)
                f[e] = p[(size_t)e * 129600];
#pragma unroll
            for (int e = 0; e < 8; ++e)
                bfr[nt][e] = (short)f2bf(f[e]);
        }
#pragma unroll
        for (int mt = 0; mt < 4; ++mt)
#pragma unroll
            for (int nt = 0; nt < 5; ++nt)
                acc[mt][nt] = __builtin_amdgcn_mfma_f32_16x16x32_bf16(af[mt], bfr[nt], acc[mt][nt], 0, 0, 0);
    }
#pragma unroll
    for (int mt = 0; mt < 4; ++mt) {
        const int o0 = wm * 64 + mt * 16 + lg * 4;
        const float4 b4 = *reinterpret_cast<const float4*>(bcv + o0);
        const float badd[4] = { b4.x, b4.y, b4.z, b4.w };
#pragma unroll
        for (int rg = 0; rg < 4; ++rg) {
            const int o = o0 + rg;
            unsigned short* dst = XR + (size_t)(b * 128 + o) * 129600 + (size_t)kfeat * 1600 + t0;
#pragma unroll
            for (int nt = 0; nt < 5; ++nt) {
                const int n = wn * 80 + nt * 16 + lr;
                dst[n] = f2bf(acc[mt][nt][rg] + badd[rg]);
            }
        }
    }
}

// ---------------------------------------------------------------------------
// Kernel 2: partial Gram per (half,bo): G2 = R R^T over 800 tokens (96-pad),
// row 81 = ones so col 81 = partial s.  Grid 1024 (t-split x2 for BW).
__global__ __launch_bounds__(256) void k_gram(
    const unsigned short* __restrict__ XR, float* __restrict__ G2)
{
    __shared__ __align__(16) unsigned short Rs[96 * 168];
    const int tid = threadIdx.x;
    const int half = blockIdx.x & 1, bo = blockIdx.x >> 1;
    for (int i = 81 * 168 + tid; i < 96 * 168; i += 256)
        Rs[i] = (i < 82 * 168) ? (unsigned short)0x3F80 : (unsigned short)0;
    const unsigned short* Rg = XR + (size_t)bo * 129600;
    const int lane = tid & 63, wid = tid >> 6;
    const int wm = wid >> 1, wn = wid & 1;
    const int lr = lane & 15, lg = lane >> 4;
    f32x4 acc[3][3] = {};
    for (int it = 0; it < 5; ++it) {
        const int t0 = half * 800 + it * 160;
        __syncthreads();
        for (int i = tid; i < 81 * 20; i += 256) {
            const int r = i / 20, g = i % 20;
            *reinterpret_cast<s16x8*>(&Rs[r * 168 + g * 8]) =
                *reinterpret_cast<const s16x8*>(Rg + (size_t)r * 1600 + t0 + g * 8);
        }
        __syncthreads();
#pragma unroll
        for (int kk = 0; kk < 5; ++kk) {
            const int koff = kk * 32 + lg * 8;
            s16x8 af[3], bfr[3];
#pragma unroll
            for (int mt = 0; mt < 3; ++mt)
                af[mt] = *reinterpret_cast<const s16x8*>(&Rs[(wm * 48 + mt * 16 + lr) * 168 + koff]);
#pragma unroll
            for (int nt = 0; nt < 3; ++nt)
                bfr[nt] = *reinterpret_cast<const s16x8*>(&Rs[(wn * 48 + nt * 16 + lr) * 168 + koff]);
#pragma unroll
            for (int mt = 0; mt < 3; ++mt)
#pragma unroll
                for (int nt = 0; nt < 3; ++nt)
                    acc[mt][nt] = __builtin_amdgcn_mfma_f32_16x16x32_bf16(af[mt], bfr[nt], acc[mt][nt], 0, 0, 0);
        }
    }
    float* Gb = G2 + (size_t)(half * 512 + bo) * 9216;
#pragma unroll
    for (int mt = 0; mt < 3; ++mt)
#pragma unroll
        for (int nt = 0; nt < 3; ++nt)
#pragma unroll
            for (int rg = 0; rg < 4; ++rg) {
                const int row = wm * 48 + mt * 16 + lg * 4 + rg;
                const int col = wn * 48 + nt * 16 + lr;
                Gb[row * 96 + col] = acc[mt][nt][rg];
            }
}

// ---------------------------------------------------------------------------
// Kernel 3: per (bo, q-half) small algebra (f32). Grid 1024.
// P = G Wc^T; M = Wb P + u bc^T + bb v^T + 1600 bb bc^T; N = Wa^T M / 9; m = ba^T M /9
// NT bf16 [bo][q=96][k=96]: NT[q][k<81] = N[k][q], NT[q][81] = m[q], rest 0.
__global__ __launch_bounds__(256) void k_small(
    const float* __restrict__ G2, const float* __restrict__ Wa, const float* __restrict__ ba,
    const float* __restrict__ Wb, const float* __restrict__ bb,
    const float* __restrict__ Wc, const float* __restrict__ bc,
    unsigned short* __restrict__ NT)
{
    __shared__ float Gs[82 * 82];
    __shared__ float Ws[81 * 82];
    __shared__ float Pb[81 * 82];
    __shared__ float sv[81];
    __shared__ float su[81];
    __shared__ float mq[81];
    const int tid = threadIdx.x;
    const int qh = blockIdx.x & 1, bo = blockIdx.x >> 1;
    const int q0 = qh * 48;
    const int qn = qh ? 33 : 48;           // algebra columns [q0, q0+qn) within [0,81)
    const float* Gg0 = G2 + (size_t)bo * 9216;
    const float* Gg1 = G2 + (size_t)(512 + bo) * 9216;
    for (int i = tid; i < 82 * 82; i += 256) {
        const int r = i / 82, c = i % 82;
        Gs[i] = Gg0[r * 96 + c] + Gg1[r * 96 + c];
    }
    for (int i = tid; i < 81 * 81; i += 256) {
        const int r = i / 81, c = i % 81;
        Ws[r * 82 + c] = Wc[i];
    }
    __syncthreads();
    if (tid < qn) { // v = Wc s (slice)
        const int q = q0 + tid;
        float a = 0.f;
        for (int l = 0; l < 81; ++l) a += Ws[q * 82 + l] * Gs[l * 82 + 81];
        sv[q] = a;
    }
    for (int i = tid; i < 81 * qn; i += 256) { // P[k][q] = sum_l G[k][l] Wc[q][l]
        const int k = i / qn, q = q0 + i % qn;
        float a = 0.f;
        for (int l = 0; l < 81; ++l) a += Gs[k * 82 + l] * Ws[q * 82 + l];
        Pb[k * 82 + q] = a;
    }
    __syncthreads();
    for (int i = tid; i < 81 * 81; i += 256) {
        const int r = i / 81, c = i % 81;
        Ws[r * 82 + c] = Wb[i];
    }
    __syncthreads();
    if (tid < 81) { // u = Wb s (full)
        float a = 0.f;
        for (int k = 0; k < 81; ++k) a += Ws[tid * 82 + k] * Gs[k * 82 + 81];
        su[tid] = a;
    }
    __syncthreads();
    for (int i = tid; i < 81 * qn; i += 256) { // M -> Gs[p][q] (slice cols)
        const int p = i / qn, q = q0 + i % qn;
        float a = su[p] * bc[q] + bb[p] * (sv[q] + 1600.f * bc[q]);
        for (int k = 0; k < 81; ++k) a += Ws[p * 82 + k] * Pb[k * 82 + q];
        Gs[p * 82 + q] = a;
    }
    __syncthreads();
    for (int i = tid; i < 81 * 81; i += 256) {
        const int r = i / 81, c = i % 81;
        Ws[r * 82 + c] = Wa[i];
    }
    if (tid < qn) { // m[q] = sum_p ba[p] M[p][q] / 9
        const int q = q0 + tid;
        float a = 0.f;
        for (int p = 0; p < 81; ++p) a += ba[p] * Gs[p * 82 + q];
        mq[q] = a * (1.f / 9.f);
    }
    __syncthreads();
    // NT rows [q0, q0+48): block0 rows 0-47, block1 rows 48-95 (incl. zero pad rows)
    unsigned short* NTb = NT + (size_t)bo * 9216;
    for (int i = tid; i < 48 * 96; i += 256) {
        const int q = q0 + i / 96, k = i % 96;
        float val = 0.f;
        if (q < 81) {
            if (k < 81) {
                float a = 0.f;
                for (int p = 0; p < 81; ++p) a += Ws[p * 82 + k] * Gs[p * 82 + q];
                val = a * (1.f / 9.f);
            } else if (k == 81) {
                val = mq[q];
            }
        }
        NTb[q * 96 + k] = f2bf(val);
    }
}

// ---------------------------------------------------------------------------
// Kernel 4: y[t][q] = sum_k x~[t][k] N[k][q] + m[q], MFMA with D[q][t].
// LDS tile XOR-swizzled: elem(r,t) = r*192 + ((t>>3 ^ ((r>>3)&3)<<1)<<3) + (t&7)
// -> conflict-free 2B gathers (lg groups land on disjoint bank quads).
__global__ __launch_bounds__(256) void k_apply(
    const unsigned short* __restrict__ XR, const unsigned short* __restrict__ NT,
    float* __restrict__ out)
{
    __shared__ __align__(16) unsigned short Xs[96 * 192]; // 36.9 KB
    const int tid = threadIdx.x;
    const int bid = blockIdx.x;
    const int fifth = bid % 5, bo = bid / 5;
    // rows 81..95: row 81 = ones (adds m[q]), rest zeros; fill all 24 tb blocks.
    for (int i = tid; i < 15 * 24; i += 256) {
        const int row = 81 + i / 24, tb = i % 24;
        const short v = (row == 81) ? (short)0x3F80 : (short)0;
        s16x8 vv = { v, v, v, v, v, v, v, v };
        *reinterpret_cast<s16x8*>(&Xs[row * 192 + tb * 8]) = vv;
    }
    const int lane = tid & 63, wid = tid >> 6;
    const int wm = wid >> 1, wn = wid & 1;
    const int lr = lane & 15, lg = lane >> 4;

    const unsigned short* NTb = NT + (size_t)bo * 9216;
    s16x8 af[3][3];
#pragma unroll
    for (int mt = 0; mt < 3; ++mt)
#pragma unroll
        for (int kk = 0; kk < 3; ++kk)
            af[mt][kk] = *reinterpret_cast<const s16x8*>(
                NTb + (wm * 48 + mt * 16 + lr) * 96 + kk * 32 + lg * 8);

    const unsigned short* Rg = XR + (size_t)bo * 129600;
    float* ob = out + (size_t)bo * 129600;

    for (int it = 0; it < 2; ++it) {
        const int t0 = fifth * 320 + it * 160;
        __syncthreads();
        for (int i = tid; i < 81 * 20; i += 256) {
            const int r = i / 20, g = i % 20;
            const int sw = ((r >> 3) & 3) << 1;
            *reinterpret_cast<s16x8*>(&Xs[r * 192 + ((g ^ sw) << 3)]) =
                *reinterpret_cast<const s16x8*>(Rg + (size_t)r * 1600 + t0 + g * 8);
        }
        __syncthreads();
        f32x4 acc[3][5] = {};
#pragma unroll
        for (int nt = 0; nt < 5; ++nt) {
            const int tcol = wn * 80 + nt * 16 + lr;
            const int colbase = ((((tcol >> 3) ^ (lg << 1))) << 3) + (tcol & 7);
#pragma unroll
            for (int kk = 0; kk < 3; ++kk) {
                const int kbase = kk * 32 + lg * 8;
                s16x8 bfr;
#pragma unroll
                for (int e = 0; e < 8; ++e)
                    bfr[e] = (short)Xs[(kbase + e) * 192 + colbase];
#pragma unroll
                for (int mt = 0; mt < 3; ++mt)
                    acc[mt][nt] = __builtin_amdgcn_mfma_f32_16x16x32_bf16(af[mt][kk], bfr, acc[mt][nt], 0, 0, 0);
            }
        }
#pragma unroll
        for (int mt = 0; mt < 3; ++mt) {
            const int q0 = wm * 48 + mt * 16 + lg * 4;
#pragma unroll
            for (int rg = 0; rg < 4; ++rg) {
                const int q = q0 + rg;
                if (q < 81) {
                    const int chq = q / 9, cwq = q % 9;
#pragma unroll
                    for (int nt = 0; nt < 5; ++nt) {
                        const int t = t0 + wn * 80 + nt * 16 + lr;
                        const int hh = t / 40, ww = t % 40;
                        ob[(chq * 40 + hh) * 360 + cwq * 40 + ww] = acc[mt][nt][rg];
                    }
                }
            }
        }
    }
}

// ---------------------------------------------------------------------------
extern "C" void kernel_launch(void* const* d_in, const int* in_sizes, int n_in,
                              void* d_out, int out_size, void* d_ws, size_t ws_size,
                              hipStream_t stream)
{
    (void)in_sizes; (void)n_in; (void)out_size; (void)ws_size;
    const float* x   = (const float*)d_in[0];
    const float* Wcv = (const float*)d_in[1];
    const float* bcv = (const float*)d_in[2];
    const float* Wa  = (const float*)d_in[3];
    const float* ba  = (const float*)d_in[4];
    const float* Wb  = (const float*)d_in[5];
    const float* bbv = (const float*)d_in[6];
    const float* Wc  = (const float*)d_in[7];
    const float* bc2 = (const float*)d_in[8];
    float* out = (float*)d_out;

    // ws: XR bf16 132,710,400 | G2 f32 2x512x9216x4 = 37,748,736 | NT 9,437,184 | Wbf 32,768
    unsigned short* XR = (unsigned short*)d_ws;
    float* G2 = (float*)((char*)d_ws + 132710400ull);
    unsigned short* NT = (unsigned short*)((char*)d_ws + 132710400ull + 37748736ull);
    unsigned short* Wbf = (unsigned short*)((char*)d_ws + 132710400ull + 37748736ull + 9437184ull);

    k_wprep<<<64,   256, 0, stream>>>(Wcv, Wbf);
    k_conv <<<3240, 256, 0, stream>>>(x, Wbf, bcv, XR);
    k_gram <<<1024, 256, 0, stream>>>(XR, G2);
    k_small<<<1024, 256, 0, stream>>>(G2, Wa, ba, Wb, bbv, Wc, bc2, NT);
    k_apply<<<2560, 256, 0, stream>>>(XR, NT, out);
}

// Round 4
// 468.368 us; speedup vs baseline: 1.0017x; 1.0017x over previous
//
#include <hip/hip_runtime.h>
#include <hip/hip_bf16.h>

typedef float f32x4 __attribute__((ext_vector_type(4)));
typedef short s16x8 __attribute__((ext_vector_type(8)));

#define DEVI __device__ __forceinline__

DEVI unsigned short f2bf(float f) {
    return __builtin_bit_cast(unsigned short, __float2bfloat16(f));
}

// Geometry: B=4, C=128, H=W=360, r=9, h=w=40, T=1600 tokens, R2=81 features.
// token t = hh*40+ww, feature k = ch*9+cw, pixel (ch*40+hh, cw*40+ww).

// ---------------------------------------------------------------------------
// Kernel 0: convert Wconv f32[128][128] -> bf16 (L2-resident A operand).
__global__ __launch_bounds__(256) void k_wprep(
    const float* __restrict__ W, unsigned short* __restrict__ Wbf)
{
    const int i = blockIdx.x * 256 + threadIdx.x; // grid 64*256 = 16384
    Wbf[i] = f2bf(W[i]);
}

// ---------------------------------------------------------------------------
// Kernel 1: 1x1 conv GEMM. float4 global loads (160B segments) -> LDS
// [n][136c] with XOR swizzle c' = c ^ (((n>>2)&3)<<3):
//   writes ~2-way banks (vs 20-way in the unswizzled layout),
//   b128 frag reads 2-way (free). A-frags from bf16 W (L1-resident).
// XR: bf16 [bo=512][81][1600]
__global__ __launch_bounds__(256, 3) void k_conv(
    const float* __restrict__ x, const unsigned short* __restrict__ Wbf,
    const float* __restrict__ bcv, unsigned short* __restrict__ XR)
{
    __shared__ __align__(16) unsigned short Xs[160 * 136]; // 43.5 KB
    const int tid = threadIdx.x;
    int bid = blockIdx.x;
    const int rb = bid % 10; bid /= 10;
    const int cw = bid % 9;  bid /= 9;
    const int ch = bid % 9;  const int b = bid / 9;
    const int H0 = ch * 40 + rb * 4, w0 = cw * 40;
    const int kfeat = ch * 9 + cw;
    const int t0 = rb * 160;

    // Stage: 5120 float4 segments = 128c x 4hh x 10 quads; seg = hh*128 + c
    // keeps ~6 consecutive c per wave (bank spread) and 160B row segments.
    const float* xb = x + (size_t)b * 128 * 129600;
    for (int i = tid; i < 5120; i += 256) {
        const int sub = i % 10, seg = i / 10;
        const int c = seg & 127, hh = seg >> 7;
        const float4 v = *reinterpret_cast<const float4*>(
            xb + (size_t)c * 129600 + (size_t)(H0 + hh) * 360 + w0 + sub * 4);
        const int n0 = hh * 40 + sub * 4;
        const int cs = c ^ ((((10 * hh + sub)) & 3) << 3); // (n>>2)&3 const over j
        Xs[(n0 + 0) * 136 + cs] = f2bf(v.x);
        Xs[(n0 + 1) * 136 + cs] = f2bf(v.y);
        Xs[(n0 + 2) * 136 + cs] = f2bf(v.z);
        Xs[(n0 + 3) * 136 + cs] = f2bf(v.w);
    }
    __syncthreads();

    const int lane = tid & 63, wid = tid >> 6;
    const int wm = wid >> 1, wn = wid & 1;
    const int lr = lane & 15, lg = lane >> 4;

    f32x4 acc[4][5] = {};
#pragma unroll
    for (int kk = 0; kk < 4; ++kk) {
        const int c0 = kk * 32 + lg * 8;
        s16x8 af[4], bfr[5];
#pragma unroll
        for (int mt = 0; mt < 4; ++mt)
            af[mt] = *reinterpret_cast<const s16x8*>(
                Wbf + (wm * 64 + mt * 16 + lr) * 128 + c0);
#pragma unroll
        for (int nt = 0; nt < 5; ++nt) {
            const int n = wn * 80 + nt * 16 + lr;
            const int cs = c0 ^ (((n >> 2) & 3) << 3);
            bfr[nt] = *reinterpret_cast<const s16x8*>(&Xs[n * 136 + cs]);
        }
#pragma unroll
        for (int mt = 0; mt < 4; ++mt)
#pragma unroll
            for (int nt = 0; nt < 5; ++nt)
                acc[mt][nt] = __builtin_amdgcn_mfma_f32_16x16x32_bf16(af[mt], bfr[nt], acc[mt][nt], 0, 0, 0);
    }
#pragma unroll
    for (int mt = 0; mt < 4; ++mt) {
        const int o0 = wm * 64 + mt * 16 + lg * 4;
        const float4 b4 = *reinterpret_cast<const float4*>(bcv + o0);
        const float badd[4] = { b4.x, b4.y, b4.z, b4.w };
#pragma unroll
        for (int rg = 0; rg < 4; ++rg) {
            const int o = o0 + rg;
            unsigned short* dst = XR + (size_t)(b * 128 + o) * 129600 + (size_t)kfeat * 1600 + t0;
#pragma unroll
            for (int nt = 0; nt < 5; ++nt) {
                const int n = wn * 80 + nt * 16 + lr;
                dst[n] = f2bf(acc[mt][nt][rg] + badd[rg]);
            }
        }
    }
}

// ---------------------------------------------------------------------------
// Kernel 2: partial Gram per (half,bo): G2 = R R^T over 800 tokens (96-pad),
// row 81 = ones so col 81 = partial s.  Grid 1024 (t-split x2 for BW).
__global__ __launch_bounds__(256) void k_gram(
    const unsigned short* __restrict__ XR, float* __restrict__ G2)
{
    __shared__ __align__(16) unsigned short Rs[96 * 168];
    const int tid = threadIdx.x;
    const int half = blockIdx.x & 1, bo = blockIdx.x >> 1;
    for (int i = 81 * 168 + tid; i < 96 * 168; i += 256)
        Rs[i] = (i < 82 * 168) ? (unsigned short)0x3F80 : (unsigned short)0;
    const unsigned short* Rg = XR + (size_t)bo * 129600;
    const int lane = tid & 63, wid = tid >> 6;
    const int wm = wid >> 1, wn = wid & 1;
    const int lr = lane & 15, lg = lane >> 4;
    f32x4 acc[3][3] = {};
    for (int it = 0; it < 5; ++it) {
        const int t0 = half * 800 + it * 160;
        __syncthreads();
        for (int i = tid; i < 81 * 20; i += 256) {
            const int r = i / 20, g = i % 20;
            *reinterpret_cast<s16x8*>(&Rs[r * 168 + g * 8]) =
                *reinterpret_cast<const s16x8*>(Rg + (size_t)r * 1600 + t0 + g * 8);
        }
        __syncthreads();
#pragma unroll
        for (int kk = 0; kk < 5; ++kk) {
            const int koff = kk * 32 + lg * 8;
            s16x8 af[3], bfr[3];
#pragma unroll
            for (int mt = 0; mt < 3; ++mt)
                af[mt] = *reinterpret_cast<const s16x8*>(&Rs[(wm * 48 + mt * 16 + lr) * 168 + koff]);
#pragma unroll
            for (int nt = 0; nt < 3; ++nt)
                bfr[nt] = *reinterpret_cast<const s16x8*>(&Rs[(wn * 48 + nt * 16 + lr) * 168 + koff]);
#pragma unroll
            for (int mt = 0; mt < 3; ++mt)
#pragma unroll
                for (int nt = 0; nt < 3; ++nt)
                    acc[mt][nt] = __builtin_amdgcn_mfma_f32_16x16x32_bf16(af[mt], bfr[nt], acc[mt][nt], 0, 0, 0);
        }
    }
    float* Gb = G2 + (size_t)(half * 512 + bo) * 9216;
#pragma unroll
    for (int mt = 0; mt < 3; ++mt)
#pragma unroll
        for (int nt = 0; nt < 3; ++nt)
#pragma unroll
            for (int rg = 0; rg < 4; ++rg) {
                const int row = wm * 48 + mt * 16 + lg * 4 + rg;
                const int col = wn * 48 + nt * 16 + lr;
                Gb[row * 96 + col] = acc[mt][nt][rg];
            }
}

// ---------------------------------------------------------------------------
// Kernel 3: per (bo, q-half) small algebra (f32). Grid 1024.
// P = G Wc^T; M = Wb P + u bc^T + bb v^T + 1600 bb bc^T; N = Wa^T M / 9; m = ba^T M /9
// NT bf16 [bo][q=96][k=96]: NT[q][k<81] = N[k][q], NT[q][81] = m[q], rest 0.
__global__ __launch_bounds__(256) void k_small(
    const float* __restrict__ G2, const float* __restrict__ Wa, const float* __restrict__ ba,
    const float* __restrict__ Wb, const float* __restrict__ bb,
    const float* __restrict__ Wc, const float* __restrict__ bc,
    unsigned short* __restrict__ NT)
{
    __shared__ float Gs[82 * 82];
    __shared__ float Ws[81 * 82];
    __shared__ float Pb[81 * 82];
    __shared__ float sv[81];
    __shared__ float su[81];
    __shared__ float mq[81];
    const int tid = threadIdx.x;
    const int qh = blockIdx.x & 1, bo = blockIdx.x >> 1;
    const int q0 = qh * 48;
    const int qn = qh ? 33 : 48;           // algebra columns [q0, q0+qn) within [0,81)
    const float* Gg0 = G2 + (size_t)bo * 9216;
    const float* Gg1 = G2 + (size_t)(512 + bo) * 9216;
    for (int i = tid; i < 82 * 82; i += 256) {
        const int r = i / 82, c = i % 82;
        Gs[i] = Gg0[r * 96 + c] + Gg1[r * 96 + c];
    }
    for (int i = tid; i < 81 * 81; i += 256) {
        const int r = i / 81, c = i % 81;
        Ws[r * 82 + c] = Wc[i];
    }
    __syncthreads();
    if (tid < qn) { // v = Wc s (slice)
        const int q = q0 + tid;
        float a = 0.f;
        for (int l = 0; l < 81; ++l) a += Ws[q * 82 + l] * Gs[l * 82 + 81];
        sv[q] = a;
    }
    for (int i = tid; i < 81 * qn; i += 256) { // P[k][q] = sum_l G[k][l] Wc[q][l]
        const int k = i / qn, q = q0 + i % qn;
        float a = 0.f;
        for (int l = 0; l < 81; ++l) a += Gs[k * 82 + l] * Ws[q * 82 + l];
        Pb[k * 82 + q] = a;
    }
    __syncthreads();
    for (int i = tid; i < 81 * 81; i += 256) {
        const int r = i / 81, c = i % 81;
        Ws[r * 82 + c] = Wb[i];
    }
    __syncthreads();
    if (tid < 81) { // u = Wb s (full)
        float a = 0.f;
        for (int k = 0; k < 81; ++k) a += Ws[tid * 82 + k] * Gs[k * 82 + 81];
        su[tid] = a;
    }
    __syncthreads();
    for (int i = tid; i < 81 * qn; i += 256) { // M -> Gs[p][q] (slice cols)
        const int p = i / qn, q = q0 + i % qn;
        float a = su[p] * bc[q] + bb[p] * (sv[q] + 1600.f * bc[q]);
        for (int k = 0; k < 81; ++k) a += Ws[p * 82 + k] * Pb[k * 82 + q];
        Gs[p * 82 + q] = a;
    }
    __syncthreads();
    for (int i = tid; i < 81 * 81; i += 256) {
        const int r = i / 81, c = i % 81;
        Ws[r * 82 + c] = Wa[i];
    }
    if (tid < qn) { // m[q] = sum_p ba[p] M[p][q] / 9
        const int q = q0 + tid;
        float a = 0.f;
        for (int p = 0; p < 81; ++p) a += ba[p] * Gs[p * 82 + q];
        mq[q] = a * (1.f / 9.f);
    }
    __syncthreads();
    // NT rows [q0, q0+48): block0 rows 0-47, block1 rows 48-95 (incl. zero pad rows)
    unsigned short* NTb = NT + (size_t)bo * 9216;
    for (int i = tid; i < 48 * 96; i += 256) {
        const int q = q0 + i / 96, k = i % 96;
        float val = 0.f;
        if (q < 81) {
            if (k < 81) {
                float a = 0.f;
                for (int p = 0; p < 81; ++p) a += Ws[p * 82 + k] * Gs[p * 82 + q];
                val = a * (1.f / 9.f);
            } else if (k == 81) {
                val = mq[q];
            }
        }
        NTb[q * 96 + k] = f2bf(val);
    }
}

// ---------------------------------------------------------------------------
// Kernel 4: y[t][q] = sum_k x~[t][k] N[k][q] + m[q], MFMA with D[q][t].
// LDS tile XOR-swizzled (verified conflict-free reads in R3).
__global__ __launch_bounds__(256) void k_apply(
    const unsigned short* __restrict__ XR, const unsigned short* __restrict__ NT,
    float* __restrict__ out)
{
    __shared__ __align__(16) unsigned short Xs[96 * 192]; // 36.9 KB
    const int tid = threadIdx.x;
    const int bid = blockIdx.x;
    const int fifth = bid % 5, bo = bid / 5;
    // rows 81..95: row 81 = ones (adds m[q]), rest zeros; fill all 24 tb blocks.
    for (int i = tid; i < 15 * 24; i += 256) {
        const int row = 81 + i / 24, tb = i % 24;
        const short v = (row == 81) ? (short)0x3F80 : (short)0;
        s16x8 vv = { v, v, v, v, v, v, v, v };
        *reinterpret_cast<s16x8*>(&Xs[row * 192 + tb * 8]) = vv;
    }
    const int lane = tid & 63, wid = tid >> 6;
    const int wm = wid >> 1, wn = wid & 1;
    const int lr = lane & 15, lg = lane >> 4;

    const unsigned short* NTb = NT + (size_t)bo * 9216;
    s16x8 af[3][3];
#pragma unroll
    for (int mt = 0; mt < 3; ++mt)
#pragma unroll
        for (int kk = 0; kk < 3; ++kk)
            af[mt][kk] = *reinterpret_cast<const s16x8*>(
                NTb + (wm * 48 + mt * 16 + lr) * 96 + kk * 32 + lg * 8);

    const unsigned short* Rg = XR + (size_t)bo * 129600;
    float* ob = out + (size_t)bo * 129600;

    for (int it = 0; it < 2; ++it) {
        const int t0 = fifth * 320 + it * 160;
        __syncthreads();
        for (int i = tid; i < 81 * 20; i += 256) {
            const int r = i / 20, g = i % 20;
            const int sw = ((r >> 3) & 3) << 1;
            *reinterpret_cast<s16x8*>(&Xs[r * 192 + ((g ^ sw) << 3)]) =
                *reinterpret_cast<const s16x8*>(Rg + (size_t)r * 1600 + t0 + g * 8);
        }
        __syncthreads();
        f32x4 acc[3][5] = {};
#pragma unroll
        for (int nt = 0; nt < 5; ++nt) {
            const int tcol = wn * 80 + nt * 16 + lr;
            const int colbase = ((((tcol >> 3) ^ (lg << 1))) << 3) + (tcol & 7);
#pragma unroll
            for (int kk = 0; kk < 3; ++kk) {
                const int kbase = kk * 32 + lg * 8;
                s16x8 bfr;
#pragma unroll
                for (int e = 0; e < 8; ++e)
                    bfr[e] = (short)Xs[(kbase + e) * 192 + colbase];
#pragma unroll
                for (int mt = 0; mt < 3; ++mt)
                    acc[mt][nt] = __builtin_amdgcn_mfma_f32_16x16x32_bf16(af[mt][kk], bfr, acc[mt][nt], 0, 0, 0);
            }
        }
#pragma unroll
        for (int mt = 0; mt < 3; ++mt) {
            const int q0 = wm * 48 + mt * 16 + lg * 4;
#pragma unroll
            for (int rg = 0; rg < 4; ++rg) {
                const int q = q0 + rg;
                if (q < 81) {
                    const int chq = q / 9, cwq = q % 9;
#pragma unroll
                    for (int nt = 0; nt < 5; ++nt) {
                        const int t = t0 + wn * 80 + nt * 16 + lr;
                        const int hh = t / 40, ww = t % 40;
                        ob[(chq * 40 + hh) * 360 + cwq * 40 + ww] = acc[mt][nt][rg];
                    }
                }
            }
        }
    }
}

// ---------------------------------------------------------------------------
extern "C" void kernel_launch(void* const* d_in, const int* in_sizes, int n_in,
                              void* d_out, int out_size, void* d_ws, size_t ws_size,
                              hipStream_t stream)
{
    (void)in_sizes; (void)n_in; (void)out_size; (void)ws_size;
    const float* x   = (const float*)d_in[0];
    const float* Wcv = (const float*)d_in[1];
    const float* bcv = (const float*)d_in[2];
    const float* Wa  = (const float*)d_in[3];
    const float* ba  = (const float*)d_in[4];
    const float* Wb  = (const float*)d_in[5];
    const float* bbv = (const float*)d_in[6];
    const float* Wc  = (const float*)d_in[7];
    const float* bc2 = (const float*)d_in[8];
    float* out = (float*)d_out;

    // ws: XR bf16 132,710,400 | G2 f32 37,748,736 | NT 9,437,184 | Wbf 32,768
    unsigned short* XR = (unsigned short*)d_ws;
    float* G2 = (float*)((char*)d_ws + 132710400ull);
    unsigned short* NT = (unsigned short*)((char*)d_ws + 132710400ull + 37748736ull);
    unsigned short* Wbf = (unsigned short*)((char*)d_ws + 132710400ull + 37748736ull + 9437184ull);

    k_wprep<<<64,   256, 0, stream>>>(Wcv, Wbf);
    k_conv <<<3240, 256, 0, stream>>>(x, Wbf, bcv, XR);
    k_gram <<<1024, 256, 0, stream>>>(XR, G2);
    k_small<<<1024, 256, 0, stream>>>(G2, Wa, ba, Wb, bbv, Wc, bc2, NT);
    k_apply<<<2560, 256, 0, stream>>>(XR, NT, out);
}

// Round 5
// 457.094 us; speedup vs baseline: 1.0264x; 1.0247x over previous
//
#include <hip/hip_runtime.h>
#include <hip/hip_bf16.h>

typedef float f32x4 __attribute__((ext_vector_type(4)));
typedef short s16x8 __attribute__((ext_vector_type(8)));

#define DEVI __device__ __forceinline__

DEVI unsigned short f2bf(float f) {
    return __builtin_bit_cast(unsigned short, __float2bfloat16(f));
}

// Geometry: B=4, C=128, H=W=360, r=9, h=w=40, T=1600 tokens, R2=81 features.
// token t = hh*40+ww, feature k = ch*9+cw, pixel (ch*40+hh, cw*40+ww).
// MFMA mapping (verified R1-R4): D col = lane&15 = B-operand row,
// D row = (lane>>4)*4 + reg = A-operand row; A/B frag: row = lane&15,
// k = (lane>>4)*8 + elem.

// ---------------------------------------------------------------------------
// Kernel 0: convert Wconv f32[128][128] -> bf16 (L2-resident B operand).
__global__ __launch_bounds__(256) void k_wprep(
    const float* __restrict__ W, unsigned short* __restrict__ Wbf)
{
    const int i = blockIdx.x * 256 + threadIdx.x; // grid 64*256 = 16384
    Wbf[i] = f2bf(W[i]);
}

// ---------------------------------------------------------------------------
// Kernel 1: 1x1 conv GEMM, A = x rows (t), B = W rows (o) so acc regs hold 4
// consecutive pixels -> ushort4 C-stores. Staging: 4x float4 (4 c, same 4 n)
// -> 4x ds_write_b64 into [n][136] with cq XOR swizzle (banks ~2-way).
// XR: bf16 [bo=512][81][1600]
__global__ __launch_bounds__(256, 3) void k_conv(
    const float* __restrict__ x, const unsigned short* __restrict__ Wbf,
    const float* __restrict__ bcv, unsigned short* __restrict__ XR)
{
    __shared__ __align__(16) unsigned short Xs[160 * 136]; // 43.5 KB
    const int tid = threadIdx.x;
    int bid = blockIdx.x;
    const int rb = bid % 10; bid /= 10;
    const int cw = bid % 9;  bid /= 9;
    const int ch = bid % 9;  const int b = bid / 9;
    const int H0 = ch * 40 + rb * 4, w0 = cw * 40;
    const int kfeat = ch * 9 + cw;
    const int t0 = rb * 160;

    // Stage: 1280 items = 32 c-quads x 40 n-quads; item -> 4 float4 loads
    // (c..c+3 at pixels n0..n0+3) -> 4 ushort4 LDS writes (one per n).
    const float* xb = x + (size_t)b * 128 * 129600;
    for (int i = tid; i < 1280; i += 256) {
        const int cq = i / 40, nq = i % 40;
        const int hh = nq / 10, sub = nq % 10;
        const float* p = xb + (size_t)(cq * 4) * 129600 + (size_t)(H0 + hh) * 360 + w0 + sub * 4;
        const float4 v0 = *reinterpret_cast<const float4*>(p);
        const float4 v1 = *reinterpret_cast<const float4*>(p + 129600);
        const float4 v2 = *reinterpret_cast<const float4*>(p + 2 * 129600);
        const float4 v3 = *reinterpret_cast<const float4*>(p + 3 * 129600);
        const int n0 = hh * 40 + sub * 4;
        const int cs = (cq ^ ((((n0 >> 2)) & 7) << 1)) * 4; // swizzled col base
        ushort4 w0v = { f2bf(v0.x), f2bf(v1.x), f2bf(v2.x), f2bf(v3.x) };
        ushort4 w1v = { f2bf(v0.y), f2bf(v1.y), f2bf(v2.y), f2bf(v3.y) };
        ushort4 w2v = { f2bf(v0.z), f2bf(v1.z), f2bf(v2.z), f2bf(v3.z) };
        ushort4 w3v = { f2bf(v0.w), f2bf(v1.w), f2bf(v2.w), f2bf(v3.w) };
        *reinterpret_cast<ushort4*>(&Xs[(n0 + 0) * 136 + cs]) = w0v;
        *reinterpret_cast<ushort4*>(&Xs[(n0 + 1) * 136 + cs]) = w1v;
        *reinterpret_cast<ushort4*>(&Xs[(n0 + 2) * 136 + cs]) = w2v;
        *reinterpret_cast<ushort4*>(&Xs[(n0 + 3) * 136 + cs]) = w3v;
    }
    __syncthreads();

    const int lane = tid & 63, wid = tid >> 6;
    const int wm = wid >> 1, wn = wid & 1;  // wm: t-half (80), wn: o-half (64)
    const int lr = lane & 15, lg = lane >> 4;

    f32x4 acc[5][4] = {};
#pragma unroll
    for (int kk = 0; kk < 4; ++kk) {
        s16x8 xa[5], wb[4];
#pragma unroll
        for (int at = 0; at < 5; ++at) {
            const int n = wm * 80 + at * 16 + lr;
            const int cqs = ((kk * 8 + lg * 2) ^ (((n >> 2) & 7) << 1)) * 4;
            xa[at] = *reinterpret_cast<const s16x8*>(&Xs[n * 136 + cqs]);
        }
#pragma unroll
        for (int bt = 0; bt < 4; ++bt)
            wb[bt] = *reinterpret_cast<const s16x8*>(
                Wbf + (wn * 64 + bt * 16 + lr) * 128 + kk * 32 + lg * 8);
#pragma unroll
        for (int at = 0; at < 5; ++at)
#pragma unroll
            for (int bt = 0; bt < 4; ++bt)
                acc[at][bt] = __builtin_amdgcn_mfma_f32_16x16x32_bf16(xa[at], wb[bt], acc[at][bt], 0, 0, 0);
    }
    // Epilogue: lane holds o = wn*64+bt*16+lr, t-quad = wm*80+at*16+lg*4.
#pragma unroll
    for (int bt = 0; bt < 4; ++bt) {
        const int o = wn * 64 + bt * 16 + lr;
        const float bias = bcv[o];
        unsigned short* dst = XR + (size_t)(b * 128 + o) * 129600 + (size_t)kfeat * 1600 + t0;
#pragma unroll
        for (int at = 0; at < 5; ++at) {
            const int n0 = wm * 80 + at * 16 + lg * 4;
            ushort4 hv = { f2bf(acc[at][bt][0] + bias), f2bf(acc[at][bt][1] + bias),
                           f2bf(acc[at][bt][2] + bias), f2bf(acc[at][bt][3] + bias) };
            *reinterpret_cast<ushort4*>(&dst[n0]) = hv;
        }
    }
}

// ---------------------------------------------------------------------------
// Kernel 2: partial Gram per (half,bo): G2 = R R^T over 800 tokens (96-pad),
// row 81 = ones so col 81 = partial s.  Grid 1024 (t-split x2 for BW).
__global__ __launch_bounds__(256) void k_gram(
    const unsigned short* __restrict__ XR, float* __restrict__ G2)
{
    __shared__ __align__(16) unsigned short Rs[96 * 168];
    const int tid = threadIdx.x;
    const int half = blockIdx.x & 1, bo = blockIdx.x >> 1;
    for (int i = 81 * 168 + tid; i < 96 * 168; i += 256)
        Rs[i] = (i < 82 * 168) ? (unsigned short)0x3F80 : (unsigned short)0;
    const unsigned short* Rg = XR + (size_t)bo * 129600;
    const int lane = tid & 63, wid = tid >> 6;
    const int wm = wid >> 1, wn = wid & 1;
    const int lr = lane & 15, lg = lane >> 4;
    f32x4 acc[3][3] = {};
    for (int it = 0; it < 5; ++it) {
        const int t0 = half * 800 + it * 160;
        __syncthreads();
        for (int i = tid; i < 81 * 20; i += 256) {
            const int r = i / 20, g = i % 20;
            *reinterpret_cast<s16x8*>(&Rs[r * 168 + g * 8]) =
                *reinterpret_cast<const s16x8*>(Rg + (size_t)r * 1600 + t0 + g * 8);
        }
        __syncthreads();
#pragma unroll
        for (int kk = 0; kk < 5; ++kk) {
            const int koff = kk * 32 + lg * 8;
            s16x8 af[3], bfr[3];
#pragma unroll
            for (int mt = 0; mt < 3; ++mt)
                af[mt] = *reinterpret_cast<const s16x8*>(&Rs[(wm * 48 + mt * 16 + lr) * 168 + koff]);
#pragma unroll
            for (int nt = 0; nt < 3; ++nt)
                bfr[nt] = *reinterpret_cast<const s16x8*>(&Rs[(wn * 48 + nt * 16 + lr) * 168 + koff]);
#pragma unroll
            for (int mt = 0; mt < 3; ++mt)
#pragma unroll
                for (int nt = 0; nt < 3; ++nt)
                    acc[mt][nt] = __builtin_amdgcn_mfma_f32_16x16x32_bf16(af[mt], bfr[nt], acc[mt][nt], 0, 0, 0);
        }
    }
    float* Gb = G2 + (size_t)(half * 512 + bo) * 9216;
#pragma unroll
    for (int mt = 0; mt < 3; ++mt)
#pragma unroll
        for (int nt = 0; nt < 3; ++nt)
#pragma unroll
            for (int rg = 0; rg < 4; ++rg) {
                const int row = wm * 48 + mt * 16 + lg * 4 + rg;
                const int col = wn * 48 + nt * 16 + lr;
                Gb[row * 96 + col] = acc[mt][nt][rg];
            }
}

// ---------------------------------------------------------------------------
// Kernel 3: per (bo, q-half) small algebra (f32). Grid 1024.
// P = G Wc^T; M = Wb P + u bc^T + bb v^T + 1600 bb bc^T; N = Wa^T M / 9; m = ba^T M /9
// NT bf16 [bo][q=96][k=96]: NT[q][k<81] = N[k][q], NT[q][81] = m[q], rest 0.
__global__ __launch_bounds__(256) void k_small(
    const float* __restrict__ G2, const float* __restrict__ Wa, const float* __restrict__ ba,
    const float* __restrict__ Wb, const float* __restrict__ bb,
    const float* __restrict__ Wc, const float* __restrict__ bc,
    unsigned short* __restrict__ NT)
{
    __shared__ float Gs[82 * 82];
    __shared__ float Ws[81 * 82];
    __shared__ float Pb[81 * 82];
    __shared__ float sv[81];
    __shared__ float su[81];
    __shared__ float mq[81];
    const int tid = threadIdx.x;
    const int qh = blockIdx.x & 1, bo = blockIdx.x >> 1;
    const int q0 = qh * 48;
    const int qn = qh ? 33 : 48;           // algebra columns [q0, q0+qn) within [0,81)
    const float* Gg0 = G2 + (size_t)bo * 9216;
    const float* Gg1 = G2 + (size_t)(512 + bo) * 9216;
    for (int i = tid; i < 82 * 82; i += 256) {
        const int r = i / 82, c = i % 82;
        Gs[i] = Gg0[r * 96 + c] + Gg1[r * 96 + c];
    }
    for (int i = tid; i < 81 * 81; i += 256) {
        const int r = i / 81, c = i % 81;
        Ws[r * 82 + c] = Wc[i];
    }
    __syncthreads();
    if (tid < qn) { // v = Wc s (slice)
        const int q = q0 + tid;
        float a = 0.f;
        for (int l = 0; l < 81; ++l) a += Ws[q * 82 + l] * Gs[l * 82 + 81];
        sv[q] = a;
    }
    for (int i = tid; i < 81 * qn; i += 256) { // P[k][q] = sum_l G[k][l] Wc[q][l]
        const int k = i / qn, q = q0 + i % qn;
        float a = 0.f;
        for (int l = 0; l < 81; ++l) a += Gs[k * 82 + l] * Ws[q * 82 + l];
        Pb[k * 82 + q] = a;
    }
    __syncthreads();
    for (int i = tid; i < 81 * 81; i += 256) {
        const int r = i / 81, c = i % 81;
        Ws[r * 82 + c] = Wb[i];
    }
    __syncthreads();
    if (tid < 81) { // u = Wb s (full)
        float a = 0.f;
        for (int k = 0; k < 81; ++k) a += Ws[tid * 82 + k] * Gs[k * 82 + 81];
        su[tid] = a;
    }
    __syncthreads();
    for (int i = tid; i < 81 * qn; i += 256) { // M -> Gs[p][q] (slice cols)
        const int p = i / qn, q = q0 + i % qn;
        float a = su[p] * bc[q] + bb[p] * (sv[q] + 1600.f * bc[q]);
        for (int k = 0; k < 81; ++k) a += Ws[p * 82 + k] * Pb[k * 82 + q];
        Gs[p * 82 + q] = a;
    }
    __syncthreads();
    for (int i = tid; i < 81 * 81; i += 256) {
        const int r = i / 81, c = i % 81;
        Ws[r * 82 + c] = Wa[i];
    }
    if (tid < qn) { // m[q] = sum_p ba[p] M[p][q] / 9
        const int q = q0 + tid;
        float a = 0.f;
        for (int p = 0; p < 81; ++p) a += ba[p] * Gs[p * 82 + q];
        mq[q] = a * (1.f / 9.f);
    }
    __syncthreads();
    // NT rows [q0, q0+48): block0 rows 0-47, block1 rows 48-95 (incl. zero pad rows)
    unsigned short* NTb = NT + (size_t)bo * 9216;
    for (int i = tid; i < 48 * 96; i += 256) {
        const int q = q0 + i / 96, k = i % 96;
        float val = 0.f;
        if (q < 81) {
            if (k < 81) {
                float a = 0.f;
                for (int p = 0; p < 81; ++p) a += Ws[p * 82 + k] * Gs[p * 82 + q];
                val = a * (1.f / 9.f);
            } else if (k == 81) {
                val = mq[q];
            }
        }
        NTb[q * 96 + k] = f2bf(val);
    }
}

// ---------------------------------------------------------------------------
// Kernel 4: y[t][q] = sum_k x~[t][k] N[k][q] + m[q].
// A = x rows (t) from [t][k]-transposed LDS (b128 reads), B = NT rows (q)
// hoisted from global. acc regs = 4 consecutive t -> aligned f32x4 stores.
// Col k=81 of x-LDS = 1.0 adds m[q]; cols 82..95 x NT-zeros.
__global__ __launch_bounds__(256) void k_apply(
    const unsigned short* __restrict__ XR, const unsigned short* __restrict__ NT,
    float* __restrict__ out)
{
    __shared__ __align__(16) unsigned short Xs[160 * 104]; // 32.5 KB
    const int tid = threadIdx.x;
    const int bid = blockIdx.x;
    const int fifth = bid % 5, bo = bid / 5;
    // init k-cols 81..95 for all t: col 81 = 1.0 (m[q] via NT), rest 0.
    for (int i = tid; i < 160 * 15; i += 256) {
        const int t = i / 15, k = 81 + i % 15;
        Xs[t * 104 + k] = (k == 81) ? (unsigned short)0x3F80 : (unsigned short)0;
    }
    const int lane = tid & 63, wid = tid >> 6;
    const int wm = wid >> 1, wn = wid & 1;  // wm: t-half (80), wn: q-half (48)
    const int lr = lane & 15, lg = lane >> 4;

    const unsigned short* NTb = NT + (size_t)bo * 9216;
    s16x8 nb[3][3]; // B-frags: NT rows q, hoisted (L2)
#pragma unroll
    for (int qt = 0; qt < 3; ++qt)
#pragma unroll
        for (int kk = 0; kk < 3; ++kk)
            nb[qt][kk] = *reinterpret_cast<const s16x8*>(
                NTb + (wn * 48 + qt * 16 + lr) * 96 + kk * 32 + lg * 8);

    const unsigned short* Rg = XR + (size_t)bo * 129600;
    float* ob = out + (size_t)bo * 129600;

    for (int it = 0; it < 2; ++it) {
        const int t0 = fifth * 320 + it * 160;
        __syncthreads();
        // stage transposed: item i -> (k = i%81, t-octet g = i/81); lanes run
        // along k -> u16 write banks 2-way (free).
        for (int i = tid; i < 81 * 20; i += 256) {
            const int k = i % 81, g = i / 81;
            const s16x8 v = *reinterpret_cast<const s16x8*>(Rg + (size_t)k * 1600 + t0 + g * 8);
#pragma unroll
            for (int e = 0; e < 8; ++e)
                Xs[(g * 8 + e) * 104 + k] = (unsigned short)v[e];
        }
        __syncthreads();
        f32x4 acc[5][3] = {};
#pragma unroll
        for (int kk = 0; kk < 3; ++kk) {
            s16x8 xa[5];
#pragma unroll
            for (int at = 0; at < 5; ++at)
                xa[at] = *reinterpret_cast<const s16x8*>(
                    &Xs[(wm * 80 + at * 16 + lr) * 104 + kk * 32 + lg * 8]);
#pragma unroll
            for (int at = 0; at < 5; ++at)
#pragma unroll
                for (int qt = 0; qt < 3; ++qt)
                    acc[at][qt] = __builtin_amdgcn_mfma_f32_16x16x32_bf16(xa[at], nb[qt][kk], acc[at][qt], 0, 0, 0);
        }
        // store: lane holds q = wn*48+qt*16+lr, t-quad = t0+wm*80+at*16+lg*4
#pragma unroll
        for (int qt = 0; qt < 3; ++qt) {
            const int q = wn * 48 + qt * 16 + lr;
            if (q < 81) {
                const int chq = q / 9, cwq = q % 9;
                float* oq = ob + (size_t)chq * 40 * 360 + cwq * 40;
#pragma unroll
                for (int at = 0; at < 5; ++at) {
                    const int tt = t0 + wm * 80 + at * 16 + lg * 4;
                    const int hh = tt / 40, ww = tt % 40;
                    *reinterpret_cast<f32x4*>(&oq[hh * 360 + ww]) = acc[at][qt];
                }
            }
        }
    }
}

// ---------------------------------------------------------------------------
extern "C" void kernel_launch(void* const* d_in, const int* in_sizes, int n_in,
                              void* d_out, int out_size, void* d_ws, size_t ws_size,
                              hipStream_t stream)
{
    (void)in_sizes; (void)n_in; (void)out_size; (void)ws_size;
    const float* x   = (const float*)d_in[0];
    const float* Wcv = (const float*)d_in[1];
    const float* bcv = (const float*)d_in[2];
    const float* Wa  = (const float*)d_in[3];
    const float* ba  = (const float*)d_in[4];
    const float* Wb  = (const float*)d_in[5];
    const float* bbv = (const float*)d_in[6];
    const float* Wc  = (const float*)d_in[7];
    const float* bc2 = (const float*)d_in[8];
    float* out = (float*)d_out;

    // ws: XR bf16 132,710,400 | G2 f32 37,748,736 | NT 9,437,184 | Wbf 32,768
    unsigned short* XR = (unsigned short*)d_ws;
    float* G2 = (float*)((char*)d_ws + 132710400ull);
    unsigned short* NT = (unsigned short*)((char*)d_ws + 132710400ull + 37748736ull);
    unsigned short* Wbf = (unsigned short*)((char*)d_ws + 132710400ull + 37748736ull + 9437184ull);

    k_wprep<<<64,   256, 0, stream>>>(Wcv, Wbf);
    k_conv <<<3240, 256, 0, stream>>>(x, Wbf, bcv, XR);
    k_gram <<<1024, 256, 0, stream>>>(XR, G2);
    k_small<<<1024, 256, 0, stream>>>(G2, Wa, ba, Wb, bbv, Wc, bc2, NT);
    k_apply<<<2560, 256, 0, stream>>>(XR, NT, out);
}

// Round 6
// 325.408 us; speedup vs baseline: 1.4417x; 1.4047x over previous
//
#include <hip/hip_runtime.h>
#include <hip/hip_bf16.h>

typedef float f32x4 __attribute__((ext_vector_type(4)));
typedef short s16x8 __attribute__((ext_vector_type(8)));

#define DEVI __device__ __forceinline__

DEVI unsigned short f2bf(float f) {
    return __builtin_bit_cast(unsigned short, __float2bfloat16(f));
}

// Geometry: B=4, C=128, H=W=360, r=9, h=w=40, T=1600 tokens, R2=81 features.
// token t = hh*40+ww, feature k = ch*9+cw, pixel (ch*40+hh, cw*40+ww).
// MFMA mapping (verified R1-R5): D col = lane&15 = B-operand row,
// D row = (lane>>4)*4 + reg = A-operand row; A/B frag: row = lane&15,
// k = (lane>>4)*8 + elem.

// ---------------------------------------------------------------------------
// Kernel 0 (fused prep):
//  blocks 0..63 : Wconv f32 -> bf16
//  blocks 64..99: EAT[j][i] = EA[i][j] = sum_p WA'[p][i] WB'[p][j]  (82x82, 96-pad)
//                 where WA' = [Wa | ba], WB' = [Wb | bb]  (cols 82..95 = 0)
//                 and WCAT[l][q] = Wc[q][l] (l<81), bc[q] (l=81), else 0.
__global__ __launch_bounds__(256) void k_prep(
    const float* __restrict__ W, const float* __restrict__ Wa,
    const float* __restrict__ ba, const float* __restrict__ Wb,
    const float* __restrict__ bb, const float* __restrict__ Wc,
    const float* __restrict__ bc, unsigned short* __restrict__ Wbf,
    float* __restrict__ EAT, float* __restrict__ WCAT)
{
    const int tid = threadIdx.x, bid = blockIdx.x;
    if (bid < 64) {
        const int i = bid * 256 + tid;
        Wbf[i] = f2bf(W[i]);
        return;
    }
    const int out = (bid - 64) * 256 + tid; // 0..9215
    const int row = out / 96, col = out % 96;
    // EAT[j=row][i=col]
    float ea = 0.f;
    if (row <= 81 && col <= 81) {
        for (int p = 0; p < 81; ++p) {
            const float wa = (col < 81) ? Wa[p * 81 + col] : ba[p];
            const float wb = (row < 81) ? Wb[p * 81 + row] : bb[p];
            ea += wa * wb;
        }
    }
    EAT[out] = ea;
    // WCAT[l=row][q=col]
    float wc = 0.f;
    if (col < 81) {
        if (row < 81) wc = Wc[col * 81 + row];
        else if (row == 81) wc = bc[col];
    }
    WCAT[out] = wc;
}

// ---------------------------------------------------------------------------
// Kernel 1: 1x1 conv GEMM, A = x rows (t), B = W rows (o); acc regs hold 4
// consecutive pixels -> ushort4 C-stores. Staging: ALL 20 float4 loads issued
// first (register batch), then convert + 4x ds_write_b64 per item into
// [n][136] with cq XOR swizzle. XR: bf16 [bo=512][81][1600]
__global__ __launch_bounds__(256, 3) void k_conv(
    const float* __restrict__ x, const unsigned short* __restrict__ Wbf,
    const float* __restrict__ bcv, unsigned short* __restrict__ XR)
{
    __shared__ __align__(16) unsigned short Xs[160 * 136]; // 43.5 KB
    const int tid = threadIdx.x;
    int bid = blockIdx.x;
    const int rb = bid % 10; bid /= 10;
    const int cw = bid % 9;  bid /= 9;
    const int ch = bid % 9;  const int b = bid / 9;
    const int H0 = ch * 40 + rb * 4, w0 = cw * 40;
    const int kfeat = ch * 9 + cw;
    const int t0 = rb * 160;

    const float* xb = x + (size_t)b * 128 * 129600;
    float4 va[5][4];
#pragma unroll
    for (int ii = 0; ii < 5; ++ii) {
        const int i = tid + ii * 256;
        const int cq = i / 40, nq = i % 40;
        const int hh = nq / 10, sub = nq % 10;
        const float* p = xb + (size_t)(cq * 4) * 129600 + (size_t)(H0 + hh) * 360 + w0 + sub * 4;
        va[ii][0] = *reinterpret_cast<const float4*>(p);
        va[ii][1] = *reinterpret_cast<const float4*>(p + 129600);
        va[ii][2] = *reinterpret_cast<const float4*>(p + 2 * 129600);
        va[ii][3] = *reinterpret_cast<const float4*>(p + 3 * 129600);
    }
#pragma unroll
    for (int ii = 0; ii < 5; ++ii) {
        const int i = tid + ii * 256;
        const int cq = i / 40, nq = i % 40;
        const int hh = nq / 10, sub = nq % 10;
        const int n0 = hh * 40 + sub * 4;
        const int cs = (cq ^ ((((n0 >> 2)) & 7) << 1)) * 4;
        const float4 v0 = va[ii][0], v1 = va[ii][1], v2 = va[ii][2], v3 = va[ii][3];
        ushort4 w0v = { f2bf(v0.x), f2bf(v1.x), f2bf(v2.x), f2bf(v3.x) };
        ushort4 w1v = { f2bf(v0.y), f2bf(v1.y), f2bf(v2.y), f2bf(v3.y) };
        ushort4 w2v = { f2bf(v0.z), f2bf(v1.z), f2bf(v2.z), f2bf(v3.z) };
        ushort4 w3v = { f2bf(v0.w), f2bf(v1.w), f2bf(v2.w), f2bf(v3.w) };
        *reinterpret_cast<ushort4*>(&Xs[(n0 + 0) * 136 + cs]) = w0v;
        *reinterpret_cast<ushort4*>(&Xs[(n0 + 1) * 136 + cs]) = w1v;
        *reinterpret_cast<ushort4*>(&Xs[(n0 + 2) * 136 + cs]) = w2v;
        *reinterpret_cast<ushort4*>(&Xs[(n0 + 3) * 136 + cs]) = w3v;
    }
    __syncthreads();

    const int lane = tid & 63, wid = tid >> 6;
    const int wm = wid >> 1, wn = wid & 1;  // wm: t-half (80), wn: o-half (64)
    const int lr = lane & 15, lg = lane >> 4;

    f32x4 acc[5][4] = {};
#pragma unroll
    for (int kk = 0; kk < 4; ++kk) {
        s16x8 xa[5], wb[4];
#pragma unroll
        for (int at = 0; at < 5; ++at) {
            const int n = wm * 80 + at * 16 + lr;
            const int cqs = ((kk * 8 + lg * 2) ^ (((n >> 2) & 7) << 1)) * 4;
            xa[at] = *reinterpret_cast<const s16x8*>(&Xs[n * 136 + cqs]);
        }
#pragma unroll
        for (int bt = 0; bt < 4; ++bt)
            wb[bt] = *reinterpret_cast<const s16x8*>(
                Wbf + (wn * 64 + bt * 16 + lr) * 128 + kk * 32 + lg * 8);
#pragma unroll
        for (int at = 0; at < 5; ++at)
#pragma unroll
            for (int bt = 0; bt < 4; ++bt)
                acc[at][bt] = __builtin_amdgcn_mfma_f32_16x16x32_bf16(xa[at], wb[bt], acc[at][bt], 0, 0, 0);
    }
#pragma unroll
    for (int bt = 0; bt < 4; ++bt) {
        const int o = wn * 64 + bt * 16 + lr;
        const float bias = bcv[o];
        unsigned short* dst = XR + (size_t)(b * 128 + o) * 129600 + (size_t)kfeat * 1600 + t0;
#pragma unroll
        for (int at = 0; at < 5; ++at) {
            const int n0 = wm * 80 + at * 16 + lg * 4;
            ushort4 hv = { f2bf(acc[at][bt][0] + bias), f2bf(acc[at][bt][1] + bias),
                           f2bf(acc[at][bt][2] + bias), f2bf(acc[at][bt][3] + bias) };
            *reinterpret_cast<ushort4*>(&dst[n0]) = hv;
        }
    }
}

// ---------------------------------------------------------------------------
// Kernel 2: partial Gram per (half,bo): G2 = R R^T over 800 tokens (96-pad),
// row 81 = ones so col 81 = partial s.  Grid 1024 (t-split x2 for BW).
__global__ __launch_bounds__(256) void k_gram(
    const unsigned short* __restrict__ XR, float* __restrict__ G2)
{
    __shared__ __align__(16) unsigned short Rs[96 * 168];
    const int tid = threadIdx.x;
    const int half = blockIdx.x & 1, bo = blockIdx.x >> 1;
    for (int i = 81 * 168 + tid; i < 96 * 168; i += 256)
        Rs[i] = (i < 82 * 168) ? (unsigned short)0x3F80 : (unsigned short)0;
    const unsigned short* Rg = XR + (size_t)bo * 129600;
    const int lane = tid & 63, wid = tid >> 6;
    const int wm = wid >> 1, wn = wid & 1;
    const int lr = lane & 15, lg = lane >> 4;
    f32x4 acc[3][3] = {};
    for (int it = 0; it < 5; ++it) {
        const int t0 = half * 800 + it * 160;
        __syncthreads();
        for (int i = tid; i < 81 * 20; i += 256) {
            const int r = i / 20, g = i % 20;
            *reinterpret_cast<s16x8*>(&Rs[r * 168 + g * 8]) =
                *reinterpret_cast<const s16x8*>(Rg + (size_t)r * 1600 + t0 + g * 8);
        }
        __syncthreads();
#pragma unroll
        for (int kk = 0; kk < 5; ++kk) {
            const int koff = kk * 32 + lg * 8;
            s16x8 af[3], bfr[3];
#pragma unroll
            for (int mt = 0; mt < 3; ++mt)
                af[mt] = *reinterpret_cast<const s16x8*>(&Rs[(wm * 48 + mt * 16 + lr) * 168 + koff]);
#pragma unroll
            for (int nt = 0; nt < 3; ++nt)
                bfr[nt] = *reinterpret_cast<const s16x8*>(&Rs[(wn * 48 + nt * 16 + lr) * 168 + koff]);
#pragma unroll
            for (int mt = 0; mt < 3; ++mt)
#pragma unroll
                for (int nt = 0; nt < 3; ++nt)
                    acc[mt][nt] = __builtin_amdgcn_mfma_f32_16x16x32_bf16(af[mt], bfr[nt], acc[mt][nt], 0, 0, 0);
        }
    }
    float* Gb = G2 + (size_t)(half * 512 + bo) * 9216;
#pragma unroll
    for (int mt = 0; mt < 3; ++mt)
#pragma unroll
        for (int nt = 0; nt < 3; ++nt)
#pragma unroll
            for (int rg = 0; rg < 4; ++rg) {
                const int row = wm * 48 + mt * 16 + lg * 4 + rg;
                const int col = wn * 48 + nt * 16 + lr;
                Gb[row * 96 + col] = acc[mt][nt][rg];
            }
}

// ---------------------------------------------------------------------------
// Kernel 3: per bo: OUT = EA * Ghat * WCA^T / 9  (two 82^3 f32 matmuls,
// 6x6 register tiles). Ghat = Gram-with-sums (row/col 81 = s, corner 1600),
// symmetric -> row-vector LDS reads only. NT[q][k] = OUT[k][q].
__global__ __launch_bounds__(256) void k_small(
    const float* __restrict__ G2, const float* __restrict__ EAT,
    const float* __restrict__ WCAT, unsigned short* __restrict__ NT)
{
    __shared__ float Gs[96 * 98]; // 36.75 KB
    __shared__ float Us[96 * 98]; // 36.75 KB
    const int tid = threadIdx.x;
    const int bo = blockIdx.x;
    const int ty = tid >> 4, tx = tid & 15;
    const int r0 = ty * 6, q0 = tx * 6;

    const float* Gg0 = G2 + (size_t)bo * 9216;
    const float* Gg1 = G2 + (size_t)(512 + bo) * 9216;
    for (int i = tid; i < 96 * 96; i += 256) {
        const int r = i / 96, c = i % 96;
        Gs[r * 98 + c] = Gg0[i] + Gg1[i];
    }
    __syncthreads();

    // Matmul A: U[j][q] = sum_{l<=81} Ghat[j][l]*WCA[q][l]
    //                   = sum_l Gs[l][j] * WCAT[l][q]   (G symmetric)
    {
        float acc[6][6] = {};
        for (int l = 0; l <= 81; ++l) {
            float gv[6], wv[6];
#pragma unroll
            for (int a = 0; a < 6; ++a) gv[a] = Gs[l * 98 + r0 + a];
#pragma unroll
            for (int b2 = 0; b2 < 6; ++b2) wv[b2] = WCAT[l * 96 + q0 + b2];
#pragma unroll
            for (int a = 0; a < 6; ++a)
#pragma unroll
                for (int b2 = 0; b2 < 6; ++b2)
                    acc[a][b2] += gv[a] * wv[b2];
        }
#pragma unroll
        for (int a = 0; a < 6; ++a)
#pragma unroll
            for (int b2 = 0; b2 < 6; ++b2)
                Us[(r0 + a) * 98 + q0 + b2] = acc[a][b2];
    }
    __syncthreads();

    // Matmul B: OUT[i][q] = sum_{j<=81} EA[i][j]*U[j][q] = sum_j EAT[j][i]*Us[j][q]
    float acc[6][6] = {};
    for (int j = 0; j <= 81; ++j) {
        float ev[6], uv[6];
#pragma unroll
        for (int a = 0; a < 6; ++a) ev[a] = EAT[j * 96 + r0 + a];
#pragma unroll
        for (int b2 = 0; b2 < 6; ++b2) uv[b2] = Us[j * 98 + q0 + b2];
#pragma unroll
        for (int a = 0; a < 6; ++a)
#pragma unroll
            for (int b2 = 0; b2 < 6; ++b2)
                acc[a][b2] += ev[a] * uv[b2];
    }
    // NT[q][i] = OUT[i][q]/9
    unsigned short* NTb = NT + (size_t)bo * 9216;
#pragma unroll
    for (int b2 = 0; b2 < 6; ++b2)
#pragma unroll
        for (int a = 0; a < 6; ++a)
            NTb[(q0 + b2) * 96 + (r0 + a)] = f2bf(acc[a][b2] * (1.f / 9.f));
}

// ---------------------------------------------------------------------------
// Kernel 4: y[t][q] = sum_k x~[t][k] N[k][q] + m[q].
// A = x rows (t) from [t][k]-transposed LDS (b128 reads), B = NT rows (q)
// hoisted from global. acc regs = 4 consecutive t -> aligned f32x4 stores.
__global__ __launch_bounds__(256) void k_apply(
    const unsigned short* __restrict__ XR, const unsigned short* __restrict__ NT,
    float* __restrict__ out)
{
    __shared__ __align__(16) unsigned short Xs[160 * 104]; // 32.5 KB
    const int tid = threadIdx.x;
    const int bid = blockIdx.x;
    const int fifth = bid % 5, bo = bid / 5;
    for (int i = tid; i < 160 * 15; i += 256) {
        const int t = i / 15, k = 81 + i % 15;
        Xs[t * 104 + k] = (k == 81) ? (unsigned short)0x3F80 : (unsigned short)0;
    }
    const int lane = tid & 63, wid = tid >> 6;
    const int wm = wid >> 1, wn = wid & 1;  // wm: t-half (80), wn: q-half (48)
    const int lr = lane & 15, lg = lane >> 4;

    const unsigned short* NTb = NT + (size_t)bo * 9216;
    s16x8 nb[3][3];
#pragma unroll
    for (int qt = 0; qt < 3; ++qt)
#pragma unroll
        for (int kk = 0; kk < 3; ++kk)
            nb[qt][kk] = *reinterpret_cast<const s16x8*>(
                NTb + (wn * 48 + qt * 16 + lr) * 96 + kk * 32 + lg * 8);

    const unsigned short* Rg = XR + (size_t)bo * 129600;
    float* ob = out + (size_t)bo * 129600;

    for (int it = 0; it < 2; ++it) {
        const int t0 = fifth * 320 + it * 160;
        __syncthreads();
        for (int i = tid; i < 81 * 20; i += 256) {
            const int k = i % 81, g = i / 81;
            const s16x8 v = *reinterpret_cast<const s16x8*>(Rg + (size_t)k * 1600 + t0 + g * 8);
#pragma unroll
            for (int e = 0; e < 8; ++e)
                Xs[(g * 8 + e) * 104 + k] = (unsigned short)v[e];
        }
        __syncthreads();
        f32x4 acc[5][3] = {};
#pragma unroll
        for (int kk = 0; kk < 3; ++kk) {
            s16x8 xa[5];
#pragma unroll
            for (int at = 0; at < 5; ++at)
                xa[at] = *reinterpret_cast<const s16x8*>(
                    &Xs[(wm * 80 + at * 16 + lr) * 104 + kk * 32 + lg * 8]);
#pragma unroll
            for (int at = 0; at < 5; ++at)
#pragma unroll
                for (int qt = 0; qt < 3; ++qt)
                    acc[at][qt] = __builtin_amdgcn_mfma_f32_16x16x32_bf16(xa[at], nb[qt][kk], acc[at][qt], 0, 0, 0);
        }
#pragma unroll
        for (int qt = 0; qt < 3; ++qt) {
            const int q = wn * 48 + qt * 16 + lr;
            if (q < 81) {
                const int chq = q / 9, cwq = q % 9;
                float* oq = ob + (size_t)chq * 40 * 360 + cwq * 40;
#pragma unroll
                for (int at = 0; at < 5; ++at) {
                    const int tt = t0 + wm * 80 + at * 16 + lg * 4;
                    const int hh = tt / 40, ww = tt % 40;
                    *reinterpret_cast<f32x4*>(&oq[hh * 360 + ww]) = acc[at][qt];
                }
            }
        }
    }
}

// ---------------------------------------------------------------------------
extern "C" void kernel_launch(void* const* d_in, const int* in_sizes, int n_in,
                              void* d_out, int out_size, void* d_ws, size_t ws_size,
                              hipStream_t stream)
{
    (void)in_sizes; (void)n_in; (void)out_size; (void)ws_size;
    const float* x   = (const float*)d_in[0];
    const float* Wcv = (const float*)d_in[1];
    const float* bcv = (const float*)d_in[2];
    const float* Wa  = (const float*)d_in[3];
    const float* ba  = (const float*)d_in[4];
    const float* Wb  = (const float*)d_in[5];
    const float* bbv = (const float*)d_in[6];
    const float* Wc  = (const float*)d_in[7];
    const float* bc2 = (const float*)d_in[8];
    float* out = (float*)d_out;

    // ws: XR 132,710,400 | G2 37,748,736 | NT 9,437,184 | Wbf 32,768
    //   | EAT 36,864 | WCAT 36,864
    char* w = (char*)d_ws;
    unsigned short* XR = (unsigned short*)w;
    float* G2 = (float*)(w + 132710400ull);
    unsigned short* NT = (unsigned short*)(w + 170459136ull);
    unsigned short* Wbf = (unsigned short*)(w + 179896320ull);
    float* EAT  = (float*)(w + 179929088ull);
    float* WCAT = (float*)(w + 179965952ull);

    k_prep <<<100,  256, 0, stream>>>(Wcv, Wa, ba, Wb, bbv, Wc, bc2, Wbf, EAT, WCAT);
    k_conv <<<3240, 256, 0, stream>>>(x, Wbf, bcv, XR);
    k_gram <<<1024, 256, 0, stream>>>(XR, G2);
    k_small<<<512,  256, 0, stream>>>(G2, EAT, WCAT, NT);
    k_apply<<<2560, 256, 0, stream>>>(XR, NT, out);
}

// Round 7
// 305.550 us; speedup vs baseline: 1.5354x; 1.0650x over previous
//
#include <hip/hip_runtime.h>
#include <hip/hip_bf16.h>

typedef float f32x4 __attribute__((ext_vector_type(4)));
typedef short s16x8 __attribute__((ext_vector_type(8)));

#define DEVI __device__ __forceinline__

DEVI unsigned short f2bf(float f) {
    return __builtin_bit_cast(unsigned short, __float2bfloat16(f));
}

// Geometry: B=4, C=128, H=W=360, r=9, h=w=40, T=1600 tokens, R2=81 features.
// token t = hh*40+ww, feature k = ch*9+cw, pixel (ch*40+hh, cw*40+ww).
// MFMA mapping (verified R1-R6): D col = lane&15 = B-operand row,
// D row = (lane>>4)*4 + reg = A-operand row; A/B frag: row = lane&15,
// k = (lane>>4)*8 + elem.

// ---------------------------------------------------------------------------
// Kernel 0 (fused prep):
//  blocks 0..63 : Wconv f32 -> bf16
//  blocks 64..99: EAT[j][i] = EA[i][j] = sum_p WA'[p][i] WB'[p][j]  (82x82, 96-pad)
//                 WA' = [Wa | ba], WB' = [Wb | bb]; WCAT[l][q] = Wc[q][l]/bc[q].
__global__ __launch_bounds__(256) void k_prep(
    const float* __restrict__ W, const float* __restrict__ Wa,
    const float* __restrict__ ba, const float* __restrict__ Wb,
    const float* __restrict__ bb, const float* __restrict__ Wc,
    const float* __restrict__ bc, unsigned short* __restrict__ Wbf,
    float* __restrict__ EAT, float* __restrict__ WCAT)
{
    const int tid = threadIdx.x, bid = blockIdx.x;
    if (bid < 64) {
        const int i = bid * 256 + tid;
        Wbf[i] = f2bf(W[i]);
        return;
    }
    const int out = (bid - 64) * 256 + tid; // 0..9215
    const int row = out / 96, col = out % 96;
    float ea = 0.f;
    if (row <= 81 && col <= 81) {
        for (int p = 0; p < 81; ++p) {
            const float wa = (col < 81) ? Wa[p * 81 + col] : ba[p];
            const float wb = (row < 81) ? Wb[p * 81 + row] : bb[p];
            ea += wa * wb;
        }
    }
    EAT[out] = ea;
    float wc = 0.f;
    if (col < 81) {
        if (row < 81) wc = Wc[col * 81 + row];
        else if (row == 81) wc = bc[col];
    }
    WCAT[out] = wc;
}

// ---------------------------------------------------------------------------
// Kernel 1: 1x1 conv GEMM, A = x rows (t), B = W rows (o). Staging: batched
// float4 loads -> swizzled [n][136] LDS. NEW: epilogue bounces acc through
// LDS [o][168] then cooperatively stores contiguous 320B per o-row
// (full-line HBM writes, no RFO). XR: bf16 [bo=512][81][1600]
__global__ __launch_bounds__(256, 3) void k_conv(
    const float* __restrict__ x, const unsigned short* __restrict__ Wbf,
    const float* __restrict__ bcv, unsigned short* __restrict__ XR)
{
    __shared__ __align__(16) unsigned short Xs[160 * 136]; // 43.5 KB (reused)
    const int tid = threadIdx.x;
    int bid = blockIdx.x;
    const int rb = bid % 10; bid /= 10;
    const int cw = bid % 9;  bid /= 9;
    const int ch = bid % 9;  const int b = bid / 9;
    const int H0 = ch * 40 + rb * 4, w0 = cw * 40;
    const int kfeat = ch * 9 + cw;
    const int t0 = rb * 160;

    const float* xb = x + (size_t)b * 128 * 129600;
    float4 va[5][4];
#pragma unroll
    for (int ii = 0; ii < 5; ++ii) {
        const int i = tid + ii * 256;
        const int cq = i / 40, nq = i % 40;
        const int hh = nq / 10, sub = nq % 10;
        const float* p = xb + (size_t)(cq * 4) * 129600 + (size_t)(H0 + hh) * 360 + w0 + sub * 4;
        va[ii][0] = *reinterpret_cast<const float4*>(p);
        va[ii][1] = *reinterpret_cast<const float4*>(p + 129600);
        va[ii][2] = *reinterpret_cast<const float4*>(p + 2 * 129600);
        va[ii][3] = *reinterpret_cast<const float4*>(p + 3 * 129600);
    }
#pragma unroll
    for (int ii = 0; ii < 5; ++ii) {
        const int i = tid + ii * 256;
        const int cq = i / 40, nq = i % 40;
        const int hh = nq / 10, sub = nq % 10;
        const int n0 = hh * 40 + sub * 4;
        const int cs = (cq ^ ((((n0 >> 2)) & 7) << 1)) * 4;
        const float4 v0 = va[ii][0], v1 = va[ii][1], v2 = va[ii][2], v3 = va[ii][3];
        ushort4 w0v = { f2bf(v0.x), f2bf(v1.x), f2bf(v2.x), f2bf(v3.x) };
        ushort4 w1v = { f2bf(v0.y), f2bf(v1.y), f2bf(v2.y), f2bf(v3.y) };
        ushort4 w2v = { f2bf(v0.z), f2bf(v1.z), f2bf(v2.z), f2bf(v3.z) };
        ushort4 w3v = { f2bf(v0.w), f2bf(v1.w), f2bf(v2.w), f2bf(v3.w) };
        *reinterpret_cast<ushort4*>(&Xs[(n0 + 0) * 136 + cs]) = w0v;
        *reinterpret_cast<ushort4*>(&Xs[(n0 + 1) * 136 + cs]) = w1v;
        *reinterpret_cast<ushort4*>(&Xs[(n0 + 2) * 136 + cs]) = w2v;
        *reinterpret_cast<ushort4*>(&Xs[(n0 + 3) * 136 + cs]) = w3v;
    }
    __syncthreads();

    const int lane = tid & 63, wid = tid >> 6;
    const int wm = wid >> 1, wn = wid & 1;  // wm: t-half (80), wn: o-half (64)
    const int lr = lane & 15, lg = lane >> 4;

    f32x4 acc[5][4] = {};
#pragma unroll
    for (int kk = 0; kk < 4; ++kk) {
        s16x8 xa[5], wb[4];
#pragma unroll
        for (int at = 0; at < 5; ++at) {
            const int n = wm * 80 + at * 16 + lr;
            const int cqs = ((kk * 8 + lg * 2) ^ (((n >> 2) & 7) << 1)) * 4;
            xa[at] = *reinterpret_cast<const s16x8*>(&Xs[n * 136 + cqs]);
        }
#pragma unroll
        for (int bt = 0; bt < 4; ++bt)
            wb[bt] = *reinterpret_cast<const s16x8*>(
                Wbf + (wn * 64 + bt * 16 + lr) * 128 + kk * 32 + lg * 8);
#pragma unroll
        for (int at = 0; at < 5; ++at)
#pragma unroll
            for (int bt = 0; bt < 4; ++bt)
                acc[at][bt] = __builtin_amdgcn_mfma_f32_16x16x32_bf16(xa[at], wb[bt], acc[at][bt], 0, 0, 0);
    }
    // Epilogue bounce: acc -> LDS [o][168] (2-way banks), then coalesced store.
    __syncthreads();
#pragma unroll
    for (int bt = 0; bt < 4; ++bt) {
        const int o = wn * 64 + bt * 16 + lr;
        const float bias = bcv[o];
#pragma unroll
        for (int at = 0; at < 5; ++at) {
            const int n0 = wm * 80 + at * 16 + lg * 4;
            ushort4 hv = { f2bf(acc[at][bt][0] + bias), f2bf(acc[at][bt][1] + bias),
                           f2bf(acc[at][bt][2] + bias), f2bf(acc[at][bt][3] + bias) };
            *reinterpret_cast<ushort4*>(&Xs[o * 168 + n0]) = hv;
        }
    }
    __syncthreads();
    unsigned short* dstb = XR + (size_t)b * 128 * 129600 + (size_t)kfeat * 1600 + t0;
#pragma unroll
    for (int j = 0; j < 10; ++j) {
        const int item = tid + j * 256;      // 2560 = 128 o x 20 segs
        const int o = item / 20, s2 = item % 20;
        *reinterpret_cast<s16x8*>(dstb + (size_t)o * 129600 + s2 * 8) =
            *reinterpret_cast<const s16x8*>(&Xs[o * 168 + s2 * 8]);
    }
}

// ---------------------------------------------------------------------------
// Kernel 2: partial Gram per (half,bo): G2 = R R^T over 800 tokens (96-pad),
// row 81 = ones so col 81 = partial s.  Grid 1024 (t-split x2 for BW).
__global__ __launch_bounds__(256) void k_gram(
    const unsigned short* __restrict__ XR, float* __restrict__ G2)
{
    __shared__ __align__(16) unsigned short Rs[96 * 168];
    const int tid = threadIdx.x;
    const int half = blockIdx.x & 1, bo = blockIdx.x >> 1;
    for (int i = 81 * 168 + tid; i < 96 * 168; i += 256)
        Rs[i] = (i < 82 * 168) ? (unsigned short)0x3F80 : (unsigned short)0;
    const unsigned short* Rg = XR + (size_t)bo * 129600;
    const int lane = tid & 63, wid = tid >> 6;
    const int wm = wid >> 1, wn = wid & 1;
    const int lr = lane & 15, lg = lane >> 4;
    f32x4 acc[3][3] = {};
    for (int it = 0; it < 5; ++it) {
        const int t0 = half * 800 + it * 160;
        __syncthreads();
        for (int i = tid; i < 81 * 20; i += 256) {
            const int r = i / 20, g = i % 20;
            *reinterpret_cast<s16x8*>(&Rs[r * 168 + g * 8]) =
                *reinterpret_cast<const s16x8*>(Rg + (size_t)r * 1600 + t0 + g * 8);
        }
        __syncthreads();
#pragma unroll
        for (int kk = 0; kk < 5; ++kk) {
            const int koff = kk * 32 + lg * 8;
            s16x8 af[3], bfr[3];
#pragma unroll
            for (int mt = 0; mt < 3; ++mt)
                af[mt] = *reinterpret_cast<const s16x8*>(&Rs[(wm * 48 + mt * 16 + lr) * 168 + koff]);
#pragma unroll
            for (int nt = 0; nt < 3; ++nt)
                bfr[nt] = *reinterpret_cast<const s16x8*>(&Rs[(wn * 48 + nt * 16 + lr) * 168 + koff]);
#pragma unroll
            for (int mt = 0; mt < 3; ++mt)
#pragma unroll
                for (int nt = 0; nt < 3; ++nt)
                    acc[mt][nt] = __builtin_amdgcn_mfma_f32_16x16x32_bf16(af[mt], bfr[nt], acc[mt][nt], 0, 0, 0);
        }
    }
    float* Gb = G2 + (size_t)(half * 512 + bo) * 9216;
#pragma unroll
    for (int mt = 0; mt < 3; ++mt)
#pragma unroll
        for (int nt = 0; nt < 3; ++nt)
#pragma unroll
            for (int rg = 0; rg < 4; ++rg) {
                const int row = wm * 48 + mt * 16 + lg * 4 + rg;
                const int col = wn * 48 + nt * 16 + lr;
                Gb[row * 96 + col] = acc[mt][nt][rg];
            }
}

// ---------------------------------------------------------------------------
// Kernel 3: per bo: OUT = EA * Ghat * WCA^T / 9  (two 82^3 f32 matmuls,
// 6x6 register tiles). NT[q][k] = OUT[k][q].
__global__ __launch_bounds__(256) void k_small(
    const float* __restrict__ G2, const float* __restrict__ EAT,
    const float* __restrict__ WCAT, unsigned short* __restrict__ NT)
{
    __shared__ float Gs[96 * 98];
    __shared__ float Us[96 * 98];
    const int tid = threadIdx.x;
    const int bo = blockIdx.x;
    const int ty = tid >> 4, tx = tid & 15;
    const int r0 = ty * 6, q0 = tx * 6;

    const float* Gg0 = G2 + (size_t)bo * 9216;
    const float* Gg1 = G2 + (size_t)(512 + bo) * 9216;
    for (int i = tid; i < 96 * 96; i += 256) {
        const int r = i / 96, c = i % 96;
        Gs[r * 98 + c] = Gg0[i] + Gg1[i];
    }
    __syncthreads();

    {
        float acc[6][6] = {};
        for (int l = 0; l <= 81; ++l) {
            float gv[6], wv[6];
#pragma unroll
            for (int a = 0; a < 6; ++a) gv[a] = Gs[l * 98 + r0 + a];
#pragma unroll
            for (int b2 = 0; b2 < 6; ++b2) wv[b2] = WCAT[l * 96 + q0 + b2];
#pragma unroll
            for (int a = 0; a < 6; ++a)
#pragma unroll
                for (int b2 = 0; b2 < 6; ++b2)
                    acc[a][b2] += gv[a] * wv[b2];
        }
#pragma unroll
        for (int a = 0; a < 6; ++a)
#pragma unroll
            for (int b2 = 0; b2 < 6; ++b2)
                Us[(r0 + a) * 98 + q0 + b2] = acc[a][b2];
    }
    __syncthreads();

    float acc[6][6] = {};
    for (int j = 0; j <= 81; ++j) {
        float ev[6], uv[6];
#pragma unroll
        for (int a = 0; a < 6; ++a) ev[a] = EAT[j * 96 + r0 + a];
#pragma unroll
        for (int b2 = 0; b2 < 6; ++b2) uv[b2] = Us[j * 98 + q0 + b2];
#pragma unroll
        for (int a = 0; a < 6; ++a)
#pragma unroll
            for (int b2 = 0; b2 < 6; ++b2)
                acc[a][b2] += ev[a] * uv[b2];
    }
    unsigned short* NTb = NT + (size_t)bo * 9216;
#pragma unroll
    for (int b2 = 0; b2 < 6; ++b2)
#pragma unroll
        for (int a = 0; a < 6; ++a)
            NTb[(q0 + b2) * 96 + (r0 + a)] = f2bf(acc[a][b2] * (1.f / 9.f));
}

// ---------------------------------------------------------------------------
// Kernel 4: y[t][q] = sum_k x~[t][k] N[k][q] + m[q].
// NEW staging: 4-row x 8-t register transpose -> 8 ushort4 LDS writes/item
// into [t][128] with col8-XOR swizzle (k8 ^ ((t>>3)&7)); b128 frag reads
// stay 16B-aligned. kq=20 item fuses x[80] with ones-col 81.
__global__ __launch_bounds__(256) void k_apply(
    const unsigned short* __restrict__ XR, const unsigned short* __restrict__ NT,
    float* __restrict__ out)
{
    __shared__ __align__(16) unsigned short Xs[160 * 128]; // 40 KB
    const int tid = threadIdx.x;
    const int fifth = blockIdx.x % 5, bo = blockIdx.x / 5;
    // init zeros for logical cols 84..95 (col8 = 10 upper half, col8 = 11)
    for (int i = tid; i < 320; i += 256) {
        const int t = i >> 1, h = i & 1;
        const int s = (t >> 3) & 7;
        const ushort4 z = { 0, 0, 0, 0 };
        if (h == 0) {
            *reinterpret_cast<ushort4*>(&Xs[t * 128 + ((10 ^ s) << 3) + 4]) = z;
        } else {
            *reinterpret_cast<ushort4*>(&Xs[t * 128 + ((11 ^ s) << 3)]) = z;
            *reinterpret_cast<ushort4*>(&Xs[t * 128 + ((11 ^ s) << 3) + 4]) = z;
        }
    }
    const int lane = tid & 63, wid = tid >> 6;
    const int wm = wid >> 1, wn = wid & 1;  // wm: t-half (80), wn: q-half (48)
    const int lr = lane & 15, lg = lane >> 4;

    const unsigned short* NTb = NT + (size_t)bo * 9216;
    s16x8 nb[3][3];
#pragma unroll
    for (int qt = 0; qt < 3; ++qt)
#pragma unroll
        for (int kk = 0; kk < 3; ++kk)
            nb[qt][kk] = *reinterpret_cast<const s16x8*>(
                NTb + (wn * 48 + qt * 16 + lr) * 96 + kk * 32 + lg * 8);

    const unsigned short* Rg = XR + (size_t)bo * 129600;
    float* ob = out + (size_t)bo * 129600;

    for (int it = 0; it < 2; ++it) {
        const int t0 = fifth * 320 + it * 160;
        __syncthreads();
        for (int i = tid; i < 420; i += 256) {
            const int kq = i / 20, g = i % 20;
            if (kq < 20) {
                const unsigned short* src = Rg + (size_t)(4 * kq) * 1600 + t0 + g * 8;
                const s16x8 v0 = *reinterpret_cast<const s16x8*>(src);
                const s16x8 v1 = *reinterpret_cast<const s16x8*>(src + 1600);
                const s16x8 v2 = *reinterpret_cast<const s16x8*>(src + 3200);
                const s16x8 v3 = *reinterpret_cast<const s16x8*>(src + 4800);
                const int colb = (((kq >> 1) ^ (g & 7)) << 3) + ((kq & 1) << 2);
#pragma unroll
                for (int e = 0; e < 8; ++e) {
                    const int t = g * 8 + e;
                    ushort4 wv = { (unsigned short)v0[e], (unsigned short)v1[e],
                                   (unsigned short)v2[e], (unsigned short)v3[e] };
                    *reinterpret_cast<ushort4*>(&Xs[t * 128 + colb]) = wv;
                }
            } else {
                const s16x8 v = *reinterpret_cast<const s16x8*>(
                    Rg + (size_t)80 * 1600 + t0 + g * 8);
                const int colb = (10 ^ (g & 7)) << 3;
#pragma unroll
                for (int e = 0; e < 8; ++e) {
                    const int t = g * 8 + e;
                    ushort4 wv = { (unsigned short)v[e], (unsigned short)0x3F80, 0, 0 };
                    *reinterpret_cast<ushort4*>(&Xs[t * 128 + colb]) = wv;
                }
            }
        }
        __syncthreads();
        f32x4 acc[5][3] = {};
#pragma unroll
        for (int kk = 0; kk < 3; ++kk) {
            s16x8 xa[5];
#pragma unroll
            for (int at = 0; at < 5; ++at) {
                const int t = wm * 80 + at * 16 + lr;
                const int s = (t >> 3) & 7;
                xa[at] = *reinterpret_cast<const s16x8*>(
                    &Xs[t * 128 + (((kk * 4 + lg) ^ s) << 3)]);
            }
#pragma unroll
            for (int at = 0; at < 5; ++at)
#pragma unroll
                for (int qt = 0; qt < 3; ++qt)
                    acc[at][qt] = __builtin_amdgcn_mfma_f32_16x16x32_bf16(xa[at], nb[qt][kk], acc[at][qt], 0, 0, 0);
        }
#pragma unroll
        for (int qt = 0; qt < 3; ++qt) {
            const int q = wn * 48 + qt * 16 + lr;
            if (q < 81) {
                const int chq = q / 9, cwq = q % 9;
                float* oq = ob + (size_t)chq * 40 * 360 + cwq * 40;
#pragma unroll
                for (int at = 0; at < 5; ++at) {
                    const int tt = t0 + wm * 80 + at * 16 + lg * 4;
                    const int hh = tt / 40, ww = tt % 40;
                    *reinterpret_cast<f32x4*>(&oq[hh * 360 + ww]) = acc[at][qt];
                }
            }
        }
    }
}

// ---------------------------------------------------------------------------
extern "C" void kernel_launch(void* const* d_in, const int* in_sizes, int n_in,
                              void* d_out, int out_size, void* d_ws, size_t ws_size,
                              hipStream_t stream)
{
    (void)in_sizes; (void)n_in; (void)out_size; (void)ws_size;
    const float* x   = (const float*)d_in[0];
    const float* Wcv = (const float*)d_in[1];
    const float* bcv = (const float*)d_in[2];
    const float* Wa  = (const float*)d_in[3];
    const float* ba  = (const float*)d_in[4];
    const float* Wb  = (const float*)d_in[5];
    const float* bbv = (const float*)d_in[6];
    const float* Wc  = (const float*)d_in[7];
    const float* bc2 = (const float*)d_in[8];
    float* out = (float*)d_out;

    // ws: XR 132,710,400 | G2 37,748,736 | NT 9,437,184 | Wbf 32,768
    //   | EAT 36,864 | WCAT 36,864
    char* w = (char*)d_ws;
    unsigned short* XR = (unsigned short*)w;
    float* G2 = (float*)(w + 132710400ull);
    unsigned short* NT = (unsigned short*)(w + 170459136ull);
    unsigned short* Wbf = (unsigned short*)(w + 179896320ull);
    float* EAT  = (float*)(w + 179929088ull);
    float* WCAT = (float*)(w + 179965952ull);

    k_prep <<<100,  256, 0, stream>>>(Wcv, Wa, ba, Wb, bbv, Wc, bc2, Wbf, EAT, WCAT);
    k_conv <<<3240, 256, 0, stream>>>(x, Wbf, bcv, XR);
    k_gram <<<1024, 256, 0, stream>>>(XR, G2);
    k_small<<<512,  256, 0, stream>>>(G2, EAT, WCAT, NT);
    k_apply<<<2560, 256, 0, stream>>>(XR, NT, out);
}